// Round 8
// baseline (323.337 us; speedup 1.0000x reference)
//
#include <hip/hip_runtime.h>

// RelationLayer, round 8.
// R8: (a) pair = R6 4x4 tiling + R7 perm-free hi/lo planes: 4 waves (2m x 2n),
// each 64x64 = 4mt x 4nt frags of mfma_f32_16x16x32_f16. A-frag LDS reads
// amortize over 2x wider n (R7 was LDS-co-limited: 512 b128*12cyc vs 7450cyc
// MFMA per CU-phase); 192 MFMA/wave/layer gives ILP at 2 waves/SIMD.
// (b) out_kernel FUSED into pair tail (block (i,bp) owns its 2 pmean rows):
// t4 = leaky(pmean@w4+b4), out = leaky(t4@w5+b5)*mask computed in-block;
// pmean global round-trip and the out launch deleted.
// Split math unchanged: x=hi+lo/2048; D = hi*wh + (hi*wl + lo*wh)/2048.
// conv/stats/ab/wsplit unchanged for attribution.

#define BB 32
#define CCH 384

__device__ __forceinline__ float leaky(float x) { return fmaxf(x, 0.1f * x); }

typedef _Float16 f16x8 __attribute__((ext_vector_type(8)));
typedef float f32x4 __attribute__((ext_vector_type(4)));

union F8 { uint4 q; f16x8 h; };
union H2 { _Float16 f[2]; uint32_t u; };

__device__ __forceinline__ void split2(float d0, float d1,
                                       uint32_t& hw, uint32_t& lw) {
  H2 h, l;
  h.f[0] = (_Float16)d0; h.f[1] = (_Float16)d1;
  l.f[0] = (_Float16)((d0 - (float)h.f[0]) * 2048.0f);
  l.f[1] = (_Float16)((d1 - (float)h.f[1]) * 2048.0f);
  hw = h.u; lw = l.u;
}

// ---------------------------------------------------------------- conv ------
__global__ __launch_bounds__(256) void conv_kernel(
    const float* __restrict__ x, const float* __restrict__ mask,
    const float* __restrict__ cw0, const float* __restrict__ cw1,
    float* __restrict__ yG)
{
  __shared__ float As[32 * 36];
  __shared__ float Ws[32 * 132];
  int bx = blockIdx.x;
  int rt = bx & 63;
  int ct = bx >> 6;
  int row0 = rt * 32;
  int tid = threadIdx.x;

  const float* wbase; int wstride;
  if (ct < 2) { wbase = cw0 + ct * 128 * 512; wstride = 512; }
  else        { wbase = cw1 + (ct - 2) * 512; wstride = 1536; }

  int sr  = tid >> 3;
  int sk4 = (tid & 7) * 4;
  const float* xrow = x + (row0 + sr) * 512;
  float mval = mask[row0 + sr];

  int r4 = (tid >> 5) * 4;
  int c4 = (tid & 31) * 4;

  float acc[4][4] = {{0.f,0.f,0.f,0.f},{0.f,0.f,0.f,0.f},
                     {0.f,0.f,0.f,0.f},{0.f,0.f,0.f,0.f}};
#pragma unroll 1
  for (int k0 = 0; k0 < 512; k0 += 32) {
    float4 xv = *(const float4*)(xrow + k0 + sk4);
    float4 wv[4];
#pragma unroll
    for (int rep = 0; rep < 4; ++rep) {
      int slot = rep * 256 + tid;
      int c = slot >> 3;
      int kq4 = (slot & 7) * 4;
      wv[rep] = *(const float4*)(wbase + c * wstride + k0 + kq4);
    }
    __syncthreads();
    As[(sk4 + 0) * 36 + sr] = xv.x * mval;
    As[(sk4 + 1) * 36 + sr] = xv.y * mval;
    As[(sk4 + 2) * 36 + sr] = xv.z * mval;
    As[(sk4 + 3) * 36 + sr] = xv.w * mval;
#pragma unroll
    for (int rep = 0; rep < 4; ++rep) {
      int slot = rep * 256 + tid;
      int c = slot >> 3;
      int kq4 = (slot & 7) * 4;
      Ws[(kq4 + 0) * 132 + c] = wv[rep].x;
      Ws[(kq4 + 1) * 132 + c] = wv[rep].y;
      Ws[(kq4 + 2) * 132 + c] = wv[rep].z;
      Ws[(kq4 + 3) * 132 + c] = wv[rep].w;
    }
    __syncthreads();
#pragma unroll
    for (int kk = 0; kk < 32; ++kk) {
      float4 a = *(const float4*)&As[kk * 36 + r4];
      float4 w = *(const float4*)&Ws[kk * 132 + c4];
      float av[4] = {a.x, a.y, a.z, a.w};
      float wv2[4] = {w.x, w.y, w.z, w.w};
#pragma unroll
      for (int ri = 0; ri < 4; ++ri)
#pragma unroll
        for (int ci = 0; ci < 4; ++ci)
          acc[ri][ci] = fmaf(av[ri], wv2[ci], acc[ri][ci]);
    }
  }
#pragma unroll
  for (int ci = 0; ci < 4; ++ci)
    *(float4*)&yG[(ct * 128 + c4 + ci) * 2048 + row0 + r4] =
        make_float4(acc[0][ci], acc[1][ci], acc[2][ci], acc[3][ci]);
}

// --------------------------------------------------------------- stats ------
__global__ __launch_bounds__(256) void stats_kernel(
    const float* __restrict__ yG,
    const float* __restrict__ g0, const float* __restrict__ be0,
    const float* __restrict__ g1, const float* __restrict__ be1,
    float* __restrict__ scale, float* __restrict__ shift)
{
  int c = blockIdx.x;
  int tid = threadIdx.x;
  float s = 0.f, s2 = 0.f;
  if (c < 256) {
    const float* src = yG + c * 2048 + tid * 8;
    float4 v0 = *(const float4*)(src);
    float4 v1 = *(const float4*)(src + 4);
    s  = v0.x + v0.y + v0.z + v0.w + v1.x + v1.y + v1.z + v1.w;
    s2 = v0.x*v0.x + v0.y*v0.y + v0.z*v0.z + v0.w*v0.w
       + v1.x*v1.x + v1.y*v1.y + v1.z*v1.z + v1.w*v1.w;
  } else {
    int cc = c - 256;
    const float* p0 = yG + (256 + cc) * 2048;
    const float* p1 = yG + (384 + cc) * 2048;
    const float* p2 = yG + (512 + cc) * 2048;
#pragma unroll
    for (int j = 0; j < 8; ++j) {
      int e = tid * 8 + j;
      float v = p1[e];
      if (e >= 32)   v += p0[e - 32];
      if (e < 2016)  v += p2[e + 32];
      s += v; s2 += v * v;
    }
  }
#pragma unroll
  for (int off = 32; off > 0; off >>= 1) {
    s  += __shfl_down(s, off);
    s2 += __shfl_down(s2, off);
  }
  __shared__ float rs[4], rs2[4];
  int wid = tid >> 6;
  if ((tid & 63) == 0) { rs[wid] = s; rs2[wid] = s2; }
  __syncthreads();
  if (tid == 0) {
    float S  = rs[0] + rs[1] + rs[2] + rs[3];
    float S2 = rs2[0] + rs2[1] + rs2[2] + rs2[3];
    float mean = S * (1.f / 2048.f);
    float var  = S2 * (1.f / 2048.f) - mean * mean;
    float g  = (c < 256) ? g0[c] : g1[c - 256];
    float be = (c < 256) ? be0[c] : be1[c - 256];
    float sc = g / sqrtf(var + 1e-5f);
    scale[c] = sc;
    shift[c] = be - mean * sc;
  }
}

// ------------------------------------------------------------------ ab ------
__global__ __launch_bounds__(256) void ab_kernel(
    const float* __restrict__ yG, const float* __restrict__ scale,
    const float* __restrict__ shift, const float* __restrict__ mask,
    const float* __restrict__ w0,
    float* __restrict__ a_arr, float* __restrict__ bb_arr)
{
  __shared__ float As[32 * 36];
  __shared__ float Ws[32 * 68];
  int bx = blockIdx.x;
  int rt = bx & 63, ct = bx >> 6;
  int row0 = rt * 32, n0 = ct * 64;
  int tid = threadIdx.x;
  int r4 = (tid >> 5) * 4;
  int n2 = (tid & 31) * 2;
  int scc = tid >> 3, srr4 = (tid & 7) * 4;
  int wnn8 = (tid & 7) * 8;
  const float* wbase = (n0 < 128) ? (w0 + n0) : (w0 + CCH * 128 + (n0 - 128));
  float4 mv = *(const float4*)(mask + row0 + srr4);

  float acc[4][2] = {{0.f, 0.f}};
#pragma unroll 1
  for (int c0 = 0; c0 < 384; c0 += 32) {
    int c = c0 + scc;
    float4 yv;
    if (c < 256) {
      yv = *(const float4*)(yG + c * 2048 + row0 + srr4);
    } else {
      int cc = c - 256;
      yv = *(const float4*)(yG + (384 + cc) * 2048 + row0 + srr4);
      if (rt > 0) {
        float4 u = *(const float4*)(yG + (256 + cc) * 2048 + row0 + srr4 - 32);
        yv.x += u.x; yv.y += u.y; yv.z += u.z; yv.w += u.w;
      }
      if (rt < 63) {
        float4 u = *(const float4*)(yG + (512 + cc) * 2048 + row0 + srr4 + 32);
        yv.x += u.x; yv.y += u.y; yv.z += u.z; yv.w += u.w;
      }
    }
    float sc = scale[c], sh = shift[c];
    float4 wv0 = *(const float4*)(wbase + c * 128 + wnn8);
    float4 wv1 = *(const float4*)(wbase + c * 128 + wnn8 + 4);
    __syncthreads();
    float4 hv;
    hv.x = leaky(fmaf(yv.x, sc, sh)) * mv.x;
    hv.y = leaky(fmaf(yv.y, sc, sh)) * mv.y;
    hv.z = leaky(fmaf(yv.z, sc, sh)) * mv.z;
    hv.w = leaky(fmaf(yv.w, sc, sh)) * mv.w;
    *(float4*)&As[scc * 36 + srr4] = hv;
    *(float4*)&Ws[scc * 68 + wnn8] = wv0;
    *(float4*)&Ws[scc * 68 + wnn8 + 4] = wv1;
    __syncthreads();
#pragma unroll
    for (int cc = 0; cc < 32; ++cc) {
      float4 a = *(const float4*)&As[cc * 36 + r4];
      float2 w = *(const float2*)&Ws[cc * 68 + n2];
      acc[0][0] = fmaf(a.x, w.x, acc[0][0]); acc[0][1] = fmaf(a.x, w.y, acc[0][1]);
      acc[1][0] = fmaf(a.y, w.x, acc[1][0]); acc[1][1] = fmaf(a.y, w.y, acc[1][1]);
      acc[2][0] = fmaf(a.z, w.x, acc[2][0]); acc[2][1] = fmaf(a.z, w.y, acc[2][1]);
      acc[3][0] = fmaf(a.w, w.x, acc[3][0]); acc[3][1] = fmaf(a.w, w.y, acc[3][1]);
    }
  }
  float* dst; int nd;
  if (n0 < 128) { dst = a_arr; nd = n0; } else { dst = bb_arr; nd = n0 - 128; }
#pragma unroll
  for (int ri = 0; ri < 4; ++ri)
    *(float2*)&dst[(row0 + r4 + ri) * 128 + nd + n2] = make_float2(acc[ri][0], acc[ri][1]);
}

// -------------------------------------------------------------- wsplit ------
__global__ __launch_bounds__(256) void wsplit_kernel(
    const float* __restrict__ w1, const float* __restrict__ w2,
    const float* __restrict__ w3, uint32_t* __restrict__ wpk)
{
  int e = blockIdx.x * 256 + threadIdx.x;   // 0..24575 (L, k2, n)
  int L = e >> 13;
  int r = e & 8191;
  int k2 = r >> 7, n = r & 127;
  int k = k2 * 2;
  const float* w = (L == 0) ? w1 : (L == 1) ? w2 : w3;
  uint32_t hw, lw;
  split2(w[k * 128 + n], w[(k + 1) * 128 + n], hw, lw);
  wpk[L * 8192 + n * 64 + k2] = hw;
  wpk[24576 + L * 8192 + n * 64 + k2] = lw;
}

// ---------------------------------------------------------------- pair ------
// grid (64,16), 256 threads = 4 waves (2m x 2n); each wave 64x64 = 4mt x 4nt.
// LDS 68KB -> 2 blocks/CU. Fused epilogue: pmean -> t4 -> out (d_out direct).
__global__ __launch_bounds__(256) void pair_kernel(
    const float* __restrict__ a_arr, const float* __restrict__ bb_arr,
    const float* __restrict__ b0, const uint32_t* __restrict__ wpk,
    const float* __restrict__ b1, const float* __restrict__ b2,
    const float* __restrict__ b3,
    const float* __restrict__ w4, const float* __restrict__ b4,
    const float* __restrict__ w5, const float* __restrict__ b5,
    const float* __restrict__ mask, float* __restrict__ out)
{
  __shared__ uint32_t Ahs[128 * 68];
  __shared__ uint32_t Als[128 * 68];
  int i = blockIdx.x, bp = blockIdx.y;
  int tid = threadIdx.x;

  // ---- init: p0 = leaky(a_i + bb_j + b0) -> split planes ----
#pragma unroll 1
  for (int it = 0; it < 8; ++it) {
    int idx = it * 256 + tid;            // 0..2047
    int r   = idx >> 4;                  // 0..127
    int k8  = (idx & 15) * 8;
    int db  = r >> 6, j = r & 63;
    int bq  = bp * 2 + db;
    const float* ap = a_arr + (i * BB + bq) * 128 + k8;
    const float* bbp = bb_arr + (j * BB + bq) * 128 + k8;
    const float* zp = b0 + k8;
    float d[8];
#pragma unroll
    for (int t = 0; t < 8; t += 4) {
      float4 av = *(const float4*)(ap + t);
      float4 bv = *(const float4*)(bbp + t);
      float4 zv = *(const float4*)(zp + t);
      d[t+0] = leaky(av.x + bv.x + zv.x);
      d[t+1] = leaky(av.y + bv.y + zv.y);
      d[t+2] = leaky(av.z + bv.z + zv.z);
      d[t+3] = leaky(av.w + bv.w + zv.w);
    }
    uint4 hq, lq;
    split2(d[0], d[1], hq.x, lq.x);
    split2(d[2], d[3], hq.y, lq.y);
    split2(d[4], d[5], hq.z, lq.z);
    split2(d[6], d[7], hq.w, lq.w);
    *(uint4*)&Ahs[r * 68 + k8 / 2] = hq;
    *(uint4*)&Als[r * 68 + k8 / 2] = lq;
  }
  __syncthreads();

  int wid = __builtin_amdgcn_readfirstlane(tid >> 6);
  int wm = wid & 1, wn = wid >> 1;       // m-half (=batch), n-half
  int lane = tid & 63;
  int m16 = lane & 15, q = lane >> 4;

  f32x4 hi[4][4], cr[4][4];

#pragma unroll 1
  for (int L = 0; L < 3; ++L) {
    const uint32_t* WhL = wpk + L * 8192;
    const uint32_t* WlL = wpk + 24576 + L * 8192;
    const float* Bv = (L == 0) ? b1 : (L == 1) ? b2 : b3;
#pragma unroll
    for (int mt = 0; mt < 4; ++mt)
#pragma unroll
      for (int nt = 0; nt < 4; ++nt) {
        hi[mt][nt] = (f32x4){0.f, 0.f, 0.f, 0.f};
        cr[mt][nt] = (f32x4){0.f, 0.f, 0.f, 0.f};
      }

    // prefetch ks=0 W frags
    F8 Wh[4], Wl[4], Whn[4], Wln[4];
#pragma unroll
    for (int nt = 0; nt < 4; ++nt) {
      int wrow = wn * 64 + nt * 16 + m16;
      Wh[nt].q = *(const uint4*)(WhL + wrow * 64 + q * 4);
      Wl[nt].q = *(const uint4*)(WlL + wrow * 64 + q * 4);
    }

#pragma unroll 1
    for (int ks = 0; ks < 4; ++ks) {
      int koff2 = ks * 16 + q * 4;
      if (ks < 3) {
#pragma unroll
        for (int nt = 0; nt < 4; ++nt) {
          int wrow = wn * 64 + nt * 16 + m16;
          Whn[nt].q = *(const uint4*)(WhL + wrow * 64 + koff2 + 16);
          Wln[nt].q = *(const uint4*)(WlL + wrow * 64 + koff2 + 16);
        }
      }
#pragma unroll
      for (int mt = 0; mt < 4; ++mt) {
        int arow = wm * 64 + mt * 16 + m16;
        F8 Ah, Al;
        Ah.q = *(const uint4*)&Ahs[arow * 68 + koff2];
        Al.q = *(const uint4*)&Als[arow * 68 + koff2];
#pragma unroll
        for (int nt = 0; nt < 4; ++nt) {
          hi[mt][nt] = __builtin_amdgcn_mfma_f32_16x16x32_f16(
              Ah.h, Wh[nt].h, hi[mt][nt], 0, 0, 0);
          cr[mt][nt] = __builtin_amdgcn_mfma_f32_16x16x32_f16(
              Ah.h, Wl[nt].h, cr[mt][nt], 0, 0, 0);
          cr[mt][nt] = __builtin_amdgcn_mfma_f32_16x16x32_f16(
              Al.h, Wh[nt].h, cr[mt][nt], 0, 0, 0);
        }
      }
#pragma unroll
      for (int nt = 0; nt < 4; ++nt) { Wh[nt] = Whn[nt]; Wl[nt] = Wln[nt]; }
    }

    float bias[4];
#pragma unroll
    for (int nt = 0; nt < 4; ++nt) bias[nt] = Bv[wn * 64 + nt * 16 + m16];

    if (L < 2) {
      __syncthreads();                   // all frag reads of this layer done
      int par = lane & 1;
#pragma unroll
      for (int mt = 0; mt < 4; ++mt)
#pragma unroll
        for (int nt = 0; nt < 4; ++nt) {
          int colw = wn * 32 + nt * 8 + (m16 >> 1);
#pragma unroll
          for (int rg = 0; rg < 4; ++rg) {
            float d = leaky(hi[mt][nt][rg] + cr[mt][nt][rg] * (1.0f / 2048.0f)
                            + bias[nt]);
            float dn = __shfl_xor(d, 1, 64);
            float de = par ? dn : d;
            float do_ = par ? d : dn;
            uint32_t hw, lw;
            split2(de, do_, hw, lw);
            int row = wm * 64 + mt * 16 + q * 4 + rg;
            if (par) Als[row * 68 + colw] = lw;
            else     Ahs[row * 68 + colw] = hw;
          }
        }
      __syncthreads();
    } else {
      // ---- j-mean + fused output MLP ----
      float s[4] = {0.f, 0.f, 0.f, 0.f};
#pragma unroll
      for (int nt = 0; nt < 4; ++nt)
#pragma unroll
        for (int mt = 0; mt < 4; ++mt)
#pragma unroll
          for (int rg = 0; rg < 4; ++rg)
            s[nt] += leaky(hi[mt][nt][rg] + cr[mt][nt][rg] * (1.0f / 2048.0f)
                           + bias[nt]);
      int browp = i * BB + bp * 2 + wm;
      float mfac = (1.0f / 64.0f) * mask[browp];
#pragma unroll
      for (int nt = 0; nt < 4; ++nt) {
        s[nt] += __shfl_xor(s[nt], 16, 64);
        s[nt] += __shfl_xor(s[nt], 32, 64);
      }
      __syncthreads();                   // Ahs/Als reads done; reuse as scratch
      float* Pm = (float*)Ahs;           // Pm[2][128], words 0..255
      float* T4 = (float*)Ahs + 256;     // T4[2][128], words 256..511
      if (lane < 16) {
#pragma unroll
        for (int nt = 0; nt < 4; ++nt)
          Pm[wm * 128 + wn * 64 + nt * 16 + m16] = s[nt] * mfac;
      }
      __syncthreads();
      {
        int row = tid >> 7, k = tid & 127;
        float t = b4[k];
#pragma unroll 8
        for (int c = 0; c < 128; ++c)
          t = fmaf(Pm[row * 128 + c], w4[c * 128 + k], t);
        T4[row * 128 + k] = leaky(t);
      }
      __syncthreads();
      {
        int row = tid >> 7, k = tid & 127;
        float o0 = b5[k], o1 = b5[k + 128], o2 = b5[k + 256], o3 = b5[k + 384];
#pragma unroll 4
        for (int c = 0; c < 128; ++c) {
          float a = T4[row * 128 + c];
          const float* wr = w5 + c * 512;
          o0 = fmaf(a, wr[k], o0);
          o1 = fmaf(a, wr[k + 128], o1);
          o2 = fmaf(a, wr[k + 256], o2);
          o3 = fmaf(a, wr[k + 384], o3);
        }
        int brow = i * BB + bp * 2 + row;
        float mv = mask[brow];
        float* dst = out + brow * 512;
        dst[k]       = leaky(o0) * mv;
        dst[k + 128] = leaky(o1) * mv;
        dst[k + 256] = leaky(o2) * mv;
        dst[k + 384] = leaky(o3) * mv;
      }
    }
  }
}

// -------------------------------------------------------------- launch ------
extern "C" void kernel_launch(void* const* d_in, const int* in_sizes, int n_in,
                              void* d_out, int out_size, void* d_ws, size_t ws_size,
                              hipStream_t stream) {
  const float* x    = (const float*)d_in[0];
  const float* mask = (const float*)d_in[1];
  const float* cw0  = (const float*)d_in[2];
  // d_in[3] conv_b0: cancels in BN
  const float* g0   = (const float*)d_in[4];
  const float* be0  = (const float*)d_in[5];
  const float* cw1  = (const float*)d_in[6];
  // d_in[7] conv_b1: cancels in BN
  const float* g1   = (const float*)d_in[8];
  const float* be1  = (const float*)d_in[9];
  const float* w0   = (const float*)d_in[10];
  const float* b0   = (const float*)d_in[11];
  const float* w1   = (const float*)d_in[12];
  const float* b1   = (const float*)d_in[13];
  const float* w2   = (const float*)d_in[14];
  const float* b2   = (const float*)d_in[15];
  const float* w3   = (const float*)d_in[16];
  const float* b3   = (const float*)d_in[17];
  const float* w4   = (const float*)d_in[18];
  const float* b4   = (const float*)d_in[19];
  const float* w5   = (const float*)d_in[20];
  const float* b5   = (const float*)d_in[21];

  float* ws     = (float*)d_ws;
  float* yG     = ws;                    // 640*2048 = 1,310,720 words
  uint32_t* wpk = (uint32_t*)(ws + 262144);  // overlays yG (dead after ab)
  float* scale  = ws + 1310720;          // 384
  float* shift  = ws + 1311104;          // 384
  float* a_arr  = ws + 1311488;          // 2048*128
  float* bb_arr = ws + 1573632;          // 2048*128
  float* outp   = (float*)d_out;

  conv_kernel<<<320, 256, 0, stream>>>(x, mask, cw0, cw1, yG);
  stats_kernel<<<384, 256, 0, stream>>>(yG, g0, be0, g1, be1, scale, shift);
  ab_kernel<<<256, 256, 0, stream>>>(yG, scale, shift, mask, w0, a_arr, bb_arr);
  wsplit_kernel<<<96, 256, 0, stream>>>(w1, w2, w3, wpk);  // after ab: yG dead
  dim3 g5(64, 16);
  pair_kernel<<<g5, 256, 0, stream>>>(a_arr, bb_arr, b0, wpk, b1, b2, b3,
                                      w4, b4, w5, b5, mask, outp);
}

// Round 9
// 276.485 us; speedup vs baseline: 1.1695x; 1.1695x over previous
//
#include <hip/hip_runtime.h>

// RelationLayer, round 9.
// R9 = R7 pair (best measured: 96.5us, VGPR 72, 8 waves/block) + R8's
// validated epilogue fusion (out_kernel + pmean round-trip deleted, -44us)
// + ks-loop fully unrolled (register renaming removes ping-pong copies).
// R8's 4x4+dbuf regression root-caused: needs ~230 VGPR, allocator gave 184
// -> spill + 1 block/CU. 64x64 waves need >=128 acc regs; R7's 64x32 shape
// keeps VGPR ~72 -> 4 waves/SIMD latency hiding.
// Split math: x=hi+lo/2048 (lo scaled to f16-normal range);
// D = hi*wh + (hi*wl + lo*wh)/2048; lo*wl (~2^-22) dropped.
// conv/stats/ab/wsplit unchanged for attribution.

#define BB 32
#define CCH 384

__device__ __forceinline__ float leaky(float x) { return fmaxf(x, 0.1f * x); }

typedef _Float16 f16x8 __attribute__((ext_vector_type(8)));
typedef float f32x4 __attribute__((ext_vector_type(4)));

union F8 { uint4 q; f16x8 h; };
union H2 { _Float16 f[2]; uint32_t u; };

__device__ __forceinline__ void split2(float d0, float d1,
                                       uint32_t& hw, uint32_t& lw) {
  H2 h, l;
  h.f[0] = (_Float16)d0; h.f[1] = (_Float16)d1;
  l.f[0] = (_Float16)((d0 - (float)h.f[0]) * 2048.0f);
  l.f[1] = (_Float16)((d1 - (float)h.f[1]) * 2048.0f);
  hw = h.u; lw = l.u;
}

// ---------------------------------------------------------------- conv ------
__global__ __launch_bounds__(256) void conv_kernel(
    const float* __restrict__ x, const float* __restrict__ mask,
    const float* __restrict__ cw0, const float* __restrict__ cw1,
    float* __restrict__ yG)
{
  __shared__ float As[32 * 36];
  __shared__ float Ws[32 * 132];
  int bx = blockIdx.x;
  int rt = bx & 63;
  int ct = bx >> 6;
  int row0 = rt * 32;
  int tid = threadIdx.x;

  const float* wbase; int wstride;
  if (ct < 2) { wbase = cw0 + ct * 128 * 512; wstride = 512; }
  else        { wbase = cw1 + (ct - 2) * 512; wstride = 1536; }

  int sr  = tid >> 3;
  int sk4 = (tid & 7) * 4;
  const float* xrow = x + (row0 + sr) * 512;
  float mval = mask[row0 + sr];

  int r4 = (tid >> 5) * 4;
  int c4 = (tid & 31) * 4;

  float acc[4][4] = {{0.f,0.f,0.f,0.f},{0.f,0.f,0.f,0.f},
                     {0.f,0.f,0.f,0.f},{0.f,0.f,0.f,0.f}};
#pragma unroll 1
  for (int k0 = 0; k0 < 512; k0 += 32) {
    float4 xv = *(const float4*)(xrow + k0 + sk4);
    float4 wv[4];
#pragma unroll
    for (int rep = 0; rep < 4; ++rep) {
      int slot = rep * 256 + tid;
      int c = slot >> 3;
      int kq4 = (slot & 7) * 4;
      wv[rep] = *(const float4*)(wbase + c * wstride + k0 + kq4);
    }
    __syncthreads();
    As[(sk4 + 0) * 36 + sr] = xv.x * mval;
    As[(sk4 + 1) * 36 + sr] = xv.y * mval;
    As[(sk4 + 2) * 36 + sr] = xv.z * mval;
    As[(sk4 + 3) * 36 + sr] = xv.w * mval;
#pragma unroll
    for (int rep = 0; rep < 4; ++rep) {
      int slot = rep * 256 + tid;
      int c = slot >> 3;
      int kq4 = (slot & 7) * 4;
      Ws[(kq4 + 0) * 132 + c] = wv[rep].x;
      Ws[(kq4 + 1) * 132 + c] = wv[rep].y;
      Ws[(kq4 + 2) * 132 + c] = wv[rep].z;
      Ws[(kq4 + 3) * 132 + c] = wv[rep].w;
    }
    __syncthreads();
#pragma unroll
    for (int kk = 0; kk < 32; ++kk) {
      float4 a = *(const float4*)&As[kk * 36 + r4];
      float4 w = *(const float4*)&Ws[kk * 132 + c4];
      float av[4] = {a.x, a.y, a.z, a.w};
      float wv2[4] = {w.x, w.y, w.z, w.w};
#pragma unroll
      for (int ri = 0; ri < 4; ++ri)
#pragma unroll
        for (int ci = 0; ci < 4; ++ci)
          acc[ri][ci] = fmaf(av[ri], wv2[ci], acc[ri][ci]);
    }
  }
#pragma unroll
  for (int ci = 0; ci < 4; ++ci)
    *(float4*)&yG[(ct * 128 + c4 + ci) * 2048 + row0 + r4] =
        make_float4(acc[0][ci], acc[1][ci], acc[2][ci], acc[3][ci]);
}

// --------------------------------------------------------------- stats ------
__global__ __launch_bounds__(256) void stats_kernel(
    const float* __restrict__ yG,
    const float* __restrict__ g0, const float* __restrict__ be0,
    const float* __restrict__ g1, const float* __restrict__ be1,
    float* __restrict__ scale, float* __restrict__ shift)
{
  int c = blockIdx.x;
  int tid = threadIdx.x;
  float s = 0.f, s2 = 0.f;
  if (c < 256) {
    const float* src = yG + c * 2048 + tid * 8;
    float4 v0 = *(const float4*)(src);
    float4 v1 = *(const float4*)(src + 4);
    s  = v0.x + v0.y + v0.z + v0.w + v1.x + v1.y + v1.z + v1.w;
    s2 = v0.x*v0.x + v0.y*v0.y + v0.z*v0.z + v0.w*v0.w
       + v1.x*v1.x + v1.y*v1.y + v1.z*v1.z + v1.w*v1.w;
  } else {
    int cc = c - 256;
    const float* p0 = yG + (256 + cc) * 2048;
    const float* p1 = yG + (384 + cc) * 2048;
    const float* p2 = yG + (512 + cc) * 2048;
#pragma unroll
    for (int j = 0; j < 8; ++j) {
      int e = tid * 8 + j;
      float v = p1[e];
      if (e >= 32)   v += p0[e - 32];
      if (e < 2016)  v += p2[e + 32];
      s += v; s2 += v * v;
    }
  }
#pragma unroll
  for (int off = 32; off > 0; off >>= 1) {
    s  += __shfl_down(s, off);
    s2 += __shfl_down(s2, off);
  }
  __shared__ float rs[4], rs2[4];
  int wid = tid >> 6;
  if ((tid & 63) == 0) { rs[wid] = s; rs2[wid] = s2; }
  __syncthreads();
  if (tid == 0) {
    float S  = rs[0] + rs[1] + rs[2] + rs[3];
    float S2 = rs2[0] + rs2[1] + rs2[2] + rs2[3];
    float mean = S * (1.f / 2048.f);
    float var  = S2 * (1.f / 2048.f) - mean * mean;
    float g  = (c < 256) ? g0[c] : g1[c - 256];
    float be = (c < 256) ? be0[c] : be1[c - 256];
    float sc = g / sqrtf(var + 1e-5f);
    scale[c] = sc;
    shift[c] = be - mean * sc;
  }
}

// ------------------------------------------------------------------ ab ------
__global__ __launch_bounds__(256) void ab_kernel(
    const float* __restrict__ yG, const float* __restrict__ scale,
    const float* __restrict__ shift, const float* __restrict__ mask,
    const float* __restrict__ w0,
    float* __restrict__ a_arr, float* __restrict__ bb_arr)
{
  __shared__ float As[32 * 36];
  __shared__ float Ws[32 * 68];
  int bx = blockIdx.x;
  int rt = bx & 63, ct = bx >> 6;
  int row0 = rt * 32, n0 = ct * 64;
  int tid = threadIdx.x;
  int r4 = (tid >> 5) * 4;
  int n2 = (tid & 31) * 2;
  int scc = tid >> 3, srr4 = (tid & 7) * 4;
  int wnn8 = (tid & 7) * 8;
  const float* wbase = (n0 < 128) ? (w0 + n0) : (w0 + CCH * 128 + (n0 - 128));
  float4 mv = *(const float4*)(mask + row0 + srr4);

  float acc[4][2] = {{0.f, 0.f}};
#pragma unroll 1
  for (int c0 = 0; c0 < 384; c0 += 32) {
    int c = c0 + scc;
    float4 yv;
    if (c < 256) {
      yv = *(const float4*)(yG + c * 2048 + row0 + srr4);
    } else {
      int cc = c - 256;
      yv = *(const float4*)(yG + (384 + cc) * 2048 + row0 + srr4);
      if (rt > 0) {
        float4 u = *(const float4*)(yG + (256 + cc) * 2048 + row0 + srr4 - 32);
        yv.x += u.x; yv.y += u.y; yv.z += u.z; yv.w += u.w;
      }
      if (rt < 63) {
        float4 u = *(const float4*)(yG + (512 + cc) * 2048 + row0 + srr4 + 32);
        yv.x += u.x; yv.y += u.y; yv.z += u.z; yv.w += u.w;
      }
    }
    float sc = scale[c], sh = shift[c];
    float4 wv0 = *(const float4*)(wbase + c * 128 + wnn8);
    float4 wv1 = *(const float4*)(wbase + c * 128 + wnn8 + 4);
    __syncthreads();
    float4 hv;
    hv.x = leaky(fmaf(yv.x, sc, sh)) * mv.x;
    hv.y = leaky(fmaf(yv.y, sc, sh)) * mv.y;
    hv.z = leaky(fmaf(yv.z, sc, sh)) * mv.z;
    hv.w = leaky(fmaf(yv.w, sc, sh)) * mv.w;
    *(float4*)&As[scc * 36 + srr4] = hv;
    *(float4*)&Ws[scc * 68 + wnn8] = wv0;
    *(float4*)&Ws[scc * 68 + wnn8 + 4] = wv1;
    __syncthreads();
#pragma unroll
    for (int cc = 0; cc < 32; ++cc) {
      float4 a = *(const float4*)&As[cc * 36 + r4];
      float2 w = *(const float2*)&Ws[cc * 68 + n2];
      acc[0][0] = fmaf(a.x, w.x, acc[0][0]); acc[0][1] = fmaf(a.x, w.y, acc[0][1]);
      acc[1][0] = fmaf(a.y, w.x, acc[1][0]); acc[1][1] = fmaf(a.y, w.y, acc[1][1]);
      acc[2][0] = fmaf(a.z, w.x, acc[2][0]); acc[2][1] = fmaf(a.z, w.y, acc[2][1]);
      acc[3][0] = fmaf(a.w, w.x, acc[3][0]); acc[3][1] = fmaf(a.w, w.y, acc[3][1]);
    }
  }
  float* dst; int nd;
  if (n0 < 128) { dst = a_arr; nd = n0; } else { dst = bb_arr; nd = n0 - 128; }
#pragma unroll
  for (int ri = 0; ri < 4; ++ri)
    *(float2*)&dst[(row0 + r4 + ri) * 128 + nd + n2] = make_float2(acc[ri][0], acc[ri][1]);
}

// -------------------------------------------------------------- wsplit ------
__global__ __launch_bounds__(256) void wsplit_kernel(
    const float* __restrict__ w1, const float* __restrict__ w2,
    const float* __restrict__ w3, uint32_t* __restrict__ wpk)
{
  int e = blockIdx.x * 256 + threadIdx.x;   // 0..24575 (L, k2, n)
  int L = e >> 13;
  int r = e & 8191;
  int k2 = r >> 7, n = r & 127;
  int k = k2 * 2;
  const float* w = (L == 0) ? w1 : (L == 1) ? w2 : w3;
  uint32_t hw, lw;
  split2(w[k * 128 + n], w[(k + 1) * 128 + n], hw, lw);
  wpk[L * 8192 + n * 64 + k2] = hw;
  wpk[24576 + L * 8192 + n * 64 + k2] = lw;
}

// ---------------------------------------------------------------- pair ------
// grid (64,16), 512 threads = 8 waves (2m x 4n). LDS 68KB -> 2 blocks/CU.
// Ahs/Als: f16 planes as u32 words, row stride 68 words (136 f16).
// Fused epilogue: j-mean -> t4 = leaky(@w4+b4) -> out = leaky(@w5+b5)*mask.
__global__ __launch_bounds__(512) void pair_kernel(
    const float* __restrict__ a_arr, const float* __restrict__ bb_arr,
    const float* __restrict__ b0, const uint32_t* __restrict__ wpk,
    const float* __restrict__ b1, const float* __restrict__ b2,
    const float* __restrict__ b3,
    const float* __restrict__ w4, const float* __restrict__ b4,
    const float* __restrict__ w5, const float* __restrict__ b5,
    const float* __restrict__ mask, float* __restrict__ out)
{
  __shared__ uint32_t Ahs[128 * 68];
  __shared__ uint32_t Als[128 * 68];
  int i = blockIdx.x, bp = blockIdx.y;
  int tid = threadIdx.x;

  // ---- init: p0 = leaky(a_i + bb_j + b0) -> split planes ----
#pragma unroll 1
  for (int it = 0; it < 4; ++it) {
    int idx = it * 512 + tid;            // 0..2047
    int r   = idx >> 4;                  // 0..127
    int k8  = (idx & 15) * 8;
    int db  = r >> 6, j = r & 63;
    int bq  = bp * 2 + db;
    const float* ap = a_arr + (i * BB + bq) * 128 + k8;
    const float* bbp = bb_arr + (j * BB + bq) * 128 + k8;
    const float* zp = b0 + k8;
    float d[8];
#pragma unroll
    for (int t = 0; t < 8; t += 4) {
      float4 av = *(const float4*)(ap + t);
      float4 bv = *(const float4*)(bbp + t);
      float4 zv = *(const float4*)(zp + t);
      d[t+0] = leaky(av.x + bv.x + zv.x);
      d[t+1] = leaky(av.y + bv.y + zv.y);
      d[t+2] = leaky(av.z + bv.z + zv.z);
      d[t+3] = leaky(av.w + bv.w + zv.w);
    }
    uint4 hq, lq;
    split2(d[0], d[1], hq.x, lq.x);
    split2(d[2], d[3], hq.y, lq.y);
    split2(d[4], d[5], hq.z, lq.z);
    split2(d[6], d[7], hq.w, lq.w);
    *(uint4*)&Ahs[r * 68 + k8 / 2] = hq;
    *(uint4*)&Als[r * 68 + k8 / 2] = lq;
  }
  __syncthreads();

  int wid = __builtin_amdgcn_readfirstlane(tid >> 6);
  int wm = wid & 1, wn = wid >> 1;       // m-half (=batch), n-quarter
  int lane = tid & 63;
  int m16 = lane & 15, q = lane >> 4;

  f32x4 hi[4][2], cr[4][2];

#pragma unroll 1
  for (int L = 0; L < 3; ++L) {
    const uint32_t* WhL = wpk + L * 8192;
    const uint32_t* WlL = wpk + 24576 + L * 8192;
    const float* Bv = (L == 0) ? b1 : (L == 1) ? b2 : b3;
#pragma unroll
    for (int mt = 0; mt < 4; ++mt)
#pragma unroll
      for (int nt = 0; nt < 2; ++nt) {
        hi[mt][nt] = (f32x4){0.f, 0.f, 0.f, 0.f};
        cr[mt][nt] = (f32x4){0.f, 0.f, 0.f, 0.f};
      }

    // prefetch ks=0 W frags
    F8 Wh[2], Wl[2], Whn[2], Wln[2];
#pragma unroll
    for (int nt = 0; nt < 2; ++nt) {
      int wrow = wn * 32 + nt * 16 + m16;
      Wh[nt].q = *(const uint4*)(WhL + wrow * 64 + q * 4);
      Wl[nt].q = *(const uint4*)(WlL + wrow * 64 + q * 4);
    }

#pragma unroll
    for (int ks = 0; ks < 4; ++ks) {
      int koff2 = ks * 16 + q * 4;
      if (ks < 3) {
#pragma unroll
        for (int nt = 0; nt < 2; ++nt) {
          int wrow = wn * 32 + nt * 16 + m16;
          Whn[nt].q = *(const uint4*)(WhL + wrow * 64 + koff2 + 16);
          Wln[nt].q = *(const uint4*)(WlL + wrow * 64 + koff2 + 16);
        }
      }
#pragma unroll
      for (int mt = 0; mt < 4; ++mt) {
        int arow = wm * 64 + mt * 16 + m16;
        F8 Ah, Al;
        Ah.q = *(const uint4*)&Ahs[arow * 68 + koff2];
        Al.q = *(const uint4*)&Als[arow * 68 + koff2];
#pragma unroll
        for (int nt = 0; nt < 2; ++nt) {
          hi[mt][nt] = __builtin_amdgcn_mfma_f32_16x16x32_f16(
              Ah.h, Wh[nt].h, hi[mt][nt], 0, 0, 0);
          cr[mt][nt] = __builtin_amdgcn_mfma_f32_16x16x32_f16(
              Ah.h, Wl[nt].h, cr[mt][nt], 0, 0, 0);
          cr[mt][nt] = __builtin_amdgcn_mfma_f32_16x16x32_f16(
              Al.h, Wh[nt].h, cr[mt][nt], 0, 0, 0);
        }
      }
#pragma unroll
      for (int nt = 0; nt < 2; ++nt) { Wh[nt] = Whn[nt]; Wl[nt] = Wln[nt]; }
    }

    float bias[2];
#pragma unroll
    for (int nt = 0; nt < 2; ++nt) bias[nt] = Bv[wn * 32 + nt * 16 + m16];

    if (L < 2) {
      __syncthreads();                   // all frag reads of this layer done
      int par = lane & 1;
#pragma unroll
      for (int mt = 0; mt < 4; ++mt)
#pragma unroll
        for (int nt = 0; nt < 2; ++nt) {
          int colw = (wn * 32 + nt * 16 + (m16 & ~1)) >> 1;
#pragma unroll
          for (int rg = 0; rg < 4; ++rg) {
            float d = leaky(hi[mt][nt][rg] + cr[mt][nt][rg] * (1.0f / 2048.0f)
                            + bias[nt]);
            float dn = __shfl_xor(d, 1, 64);
            float de = par ? dn : d;     // even-col value
            float do_ = par ? d : dn;    // odd-col value
            uint32_t hw, lw;
            split2(de, do_, hw, lw);
            int row = wm * 64 + mt * 16 + q * 4 + rg;
            if (par) Als[row * 68 + colw] = lw;
            else     Ahs[row * 68 + colw] = hw;
          }
        }
      __syncthreads();
    } else {
      // ---- j-mean + fused output MLP ----
      float s[2] = {0.f, 0.f};
#pragma unroll
      for (int nt = 0; nt < 2; ++nt)
#pragma unroll
        for (int mt = 0; mt < 4; ++mt)
#pragma unroll
          for (int rg = 0; rg < 4; ++rg)
            s[nt] += leaky(hi[mt][nt][rg] + cr[mt][nt][rg] * (1.0f / 2048.0f)
                           + bias[nt]);
      int browp = i * BB + bp * 2 + wm;
      float mfac = (1.0f / 64.0f) * mask[browp];
#pragma unroll
      for (int nt = 0; nt < 2; ++nt) {
        s[nt] += __shfl_xor(s[nt], 16, 64);
        s[nt] += __shfl_xor(s[nt], 32, 64);
      }
      __syncthreads();                   // Ahs/Als reads done; reuse as scratch
      float* Pm = (float*)Ahs;           // Pm[2][128], words 0..255
      float* T4 = (float*)Ahs + 256;     // T4[2][128], words 256..511
      if (lane < 16) {
#pragma unroll
        for (int nt = 0; nt < 2; ++nt)
          Pm[wm * 128 + wn * 32 + nt * 16 + m16] = s[nt] * mfac;
      }
      __syncthreads();
      if (tid < 256) {
        int row = tid >> 7, k = tid & 127;
        float t = b4[k];
#pragma unroll 8
        for (int c = 0; c < 128; ++c)
          t = fmaf(Pm[row * 128 + c], w4[c * 128 + k], t);
        T4[row * 128 + k] = leaky(t);
      }
      __syncthreads();
      {
        int row = tid >> 8, kk = tid & 255;
        float o0 = b5[kk], o1 = b5[kk + 256];
#pragma unroll 4
        for (int c = 0; c < 128; ++c) {
          float a = T4[row * 128 + c];
          const float* wr = w5 + c * 512;
          o0 = fmaf(a, wr[kk], o0);
          o1 = fmaf(a, wr[kk + 256], o1);
        }
        int brow = i * BB + bp * 2 + row;
        float mv = mask[brow];
        float* dst = out + brow * 512;
        dst[kk]       = leaky(o0) * mv;
        dst[kk + 256] = leaky(o1) * mv;
      }
    }
  }
}

// -------------------------------------------------------------- launch ------
extern "C" void kernel_launch(void* const* d_in, const int* in_sizes, int n_in,
                              void* d_out, int out_size, void* d_ws, size_t ws_size,
                              hipStream_t stream) {
  const float* x    = (const float*)d_in[0];
  const float* mask = (const float*)d_in[1];
  const float* cw0  = (const float*)d_in[2];
  // d_in[3] conv_b0: cancels in BN
  const float* g0   = (const float*)d_in[4];
  const float* be0  = (const float*)d_in[5];
  const float* cw1  = (const float*)d_in[6];
  // d_in[7] conv_b1: cancels in BN
  const float* g1   = (const float*)d_in[8];
  const float* be1  = (const float*)d_in[9];
  const float* w0   = (const float*)d_in[10];
  const float* b0   = (const float*)d_in[11];
  const float* w1   = (const float*)d_in[12];
  const float* b1   = (const float*)d_in[13];
  const float* w2   = (const float*)d_in[14];
  const float* b2   = (const float*)d_in[15];
  const float* w3   = (const float*)d_in[16];
  const float* b3   = (const float*)d_in[17];
  const float* w4   = (const float*)d_in[18];
  const float* b4   = (const float*)d_in[19];
  const float* w5   = (const float*)d_in[20];
  const float* b5   = (const float*)d_in[21];

  float* ws     = (float*)d_ws;
  float* yG     = ws;                    // 640*2048 = 1,310,720 words
  uint32_t* wpk = (uint32_t*)(ws + 262144);  // overlays yG (dead after ab)
  float* scale  = ws + 1310720;          // 384
  float* shift  = ws + 1311104;          // 384
  float* a_arr  = ws + 1311488;          // 2048*128
  float* bb_arr = ws + 1573632;          // 2048*128
  float* outp   = (float*)d_out;

  conv_kernel<<<320, 256, 0, stream>>>(x, mask, cw0, cw1, yG);
  stats_kernel<<<384, 256, 0, stream>>>(yG, g0, be0, g1, be1, scale, shift);
  ab_kernel<<<256, 256, 0, stream>>>(yG, scale, shift, mask, w0, a_arr, bb_arr);
  wsplit_kernel<<<96, 256, 0, stream>>>(w1, w2, w3, wpk);  // after ab: yG dead
  dim3 g5(64, 16);
  pair_kernel<<<g5, 512, 0, stream>>>(a_arr, bb_arr, b0, wpk, b1, b2, b3,
                                      w4, b4, w5, b5, mask, outp);
}

// Round 10
// 259.810 us; speedup vs baseline: 1.2445x; 1.0642x over previous
//
#include <hip/hip_runtime.h>

// RelationLayer, round 10.
// R10 = R9 with the fused epilogue's memory shape fixed (R9 post-mortem:
// +41us of epilogue stall -- 128-deep L2 load chains with unroll 8 after a
// barrier). Changes:
//  * out stage: 512 threads, one w5 column load serves BOTH batch rows
//    (halves w5 traffic); T4 via float4 LDS broadcasts; unroll 4 -> ~4 L2
//    round trips. t4 stage: row x c-half x k split over all 512 threads,
//    64-load chains + LDS partial combine.
//  * wsplit merged into ab_kernel (grid 352; blocks >=256 do the split) --
//    one launch deleted.
// Everything else byte-identical to R9 for attribution.

#define BB 32
#define CCH 384

__device__ __forceinline__ float leaky(float x) { return fmaxf(x, 0.1f * x); }

typedef _Float16 f16x8 __attribute__((ext_vector_type(8)));
typedef float f32x4 __attribute__((ext_vector_type(4)));

union F8 { uint4 q; f16x8 h; };
union H2 { _Float16 f[2]; uint32_t u; };

__device__ __forceinline__ void split2(float d0, float d1,
                                       uint32_t& hw, uint32_t& lw) {
  H2 h, l;
  h.f[0] = (_Float16)d0; h.f[1] = (_Float16)d1;
  l.f[0] = (_Float16)((d0 - (float)h.f[0]) * 2048.0f);
  l.f[1] = (_Float16)((d1 - (float)h.f[1]) * 2048.0f);
  hw = h.u; lw = l.u;
}

// ---------------------------------------------------------------- conv ------
__global__ __launch_bounds__(256) void conv_kernel(
    const float* __restrict__ x, const float* __restrict__ mask,
    const float* __restrict__ cw0, const float* __restrict__ cw1,
    float* __restrict__ yG)
{
  __shared__ float As[32 * 36];
  __shared__ float Ws[32 * 132];
  int bx = blockIdx.x;
  int rt = bx & 63;
  int ct = bx >> 6;
  int row0 = rt * 32;
  int tid = threadIdx.x;

  const float* wbase; int wstride;
  if (ct < 2) { wbase = cw0 + ct * 128 * 512; wstride = 512; }
  else        { wbase = cw1 + (ct - 2) * 512; wstride = 1536; }

  int sr  = tid >> 3;
  int sk4 = (tid & 7) * 4;
  const float* xrow = x + (row0 + sr) * 512;
  float mval = mask[row0 + sr];

  int r4 = (tid >> 5) * 4;
  int c4 = (tid & 31) * 4;

  float acc[4][4] = {{0.f,0.f,0.f,0.f},{0.f,0.f,0.f,0.f},
                     {0.f,0.f,0.f,0.f},{0.f,0.f,0.f,0.f}};
#pragma unroll 1
  for (int k0 = 0; k0 < 512; k0 += 32) {
    float4 xv = *(const float4*)(xrow + k0 + sk4);
    float4 wv[4];
#pragma unroll
    for (int rep = 0; rep < 4; ++rep) {
      int slot = rep * 256 + tid;
      int c = slot >> 3;
      int kq4 = (slot & 7) * 4;
      wv[rep] = *(const float4*)(wbase + c * wstride + k0 + kq4);
    }
    __syncthreads();
    As[(sk4 + 0) * 36 + sr] = xv.x * mval;
    As[(sk4 + 1) * 36 + sr] = xv.y * mval;
    As[(sk4 + 2) * 36 + sr] = xv.z * mval;
    As[(sk4 + 3) * 36 + sr] = xv.w * mval;
#pragma unroll
    for (int rep = 0; rep < 4; ++rep) {
      int slot = rep * 256 + tid;
      int c = slot >> 3;
      int kq4 = (slot & 7) * 4;
      Ws[(kq4 + 0) * 132 + c] = wv[rep].x;
      Ws[(kq4 + 1) * 132 + c] = wv[rep].y;
      Ws[(kq4 + 2) * 132 + c] = wv[rep].z;
      Ws[(kq4 + 3) * 132 + c] = wv[rep].w;
    }
    __syncthreads();
#pragma unroll
    for (int kk = 0; kk < 32; ++kk) {
      float4 a = *(const float4*)&As[kk * 36 + r4];
      float4 w = *(const float4*)&Ws[kk * 132 + c4];
      float av[4] = {a.x, a.y, a.z, a.w};
      float wv2[4] = {w.x, w.y, w.z, w.w};
#pragma unroll
      for (int ri = 0; ri < 4; ++ri)
#pragma unroll
        for (int ci = 0; ci < 4; ++ci)
          acc[ri][ci] = fmaf(av[ri], wv2[ci], acc[ri][ci]);
    }
  }
#pragma unroll
  for (int ci = 0; ci < 4; ++ci)
    *(float4*)&yG[(ct * 128 + c4 + ci) * 2048 + row0 + r4] =
        make_float4(acc[0][ci], acc[1][ci], acc[2][ci], acc[3][ci]);
}

// --------------------------------------------------------------- stats ------
__global__ __launch_bounds__(256) void stats_kernel(
    const float* __restrict__ yG,
    const float* __restrict__ g0, const float* __restrict__ be0,
    const float* __restrict__ g1, const float* __restrict__ be1,
    float* __restrict__ scale, float* __restrict__ shift)
{
  int c = blockIdx.x;
  int tid = threadIdx.x;
  float s = 0.f, s2 = 0.f;
  if (c < 256) {
    const float* src = yG + c * 2048 + tid * 8;
    float4 v0 = *(const float4*)(src);
    float4 v1 = *(const float4*)(src + 4);
    s  = v0.x + v0.y + v0.z + v0.w + v1.x + v1.y + v1.z + v1.w;
    s2 = v0.x*v0.x + v0.y*v0.y + v0.z*v0.z + v0.w*v0.w
       + v1.x*v1.x + v1.y*v1.y + v1.z*v1.z + v1.w*v1.w;
  } else {
    int cc = c - 256;
    const float* p0 = yG + (256 + cc) * 2048;
    const float* p1 = yG + (384 + cc) * 2048;
    const float* p2 = yG + (512 + cc) * 2048;
#pragma unroll
    for (int j = 0; j < 8; ++j) {
      int e = tid * 8 + j;
      float v = p1[e];
      if (e >= 32)   v += p0[e - 32];
      if (e < 2016)  v += p2[e + 32];
      s += v; s2 += v * v;
    }
  }
#pragma unroll
  for (int off = 32; off > 0; off >>= 1) {
    s  += __shfl_down(s, off);
    s2 += __shfl_down(s2, off);
  }
  __shared__ float rs[4], rs2[4];
  int wid = tid >> 6;
  if ((tid & 63) == 0) { rs[wid] = s; rs2[wid] = s2; }
  __syncthreads();
  if (tid == 0) {
    float S  = rs[0] + rs[1] + rs[2] + rs[3];
    float S2 = rs2[0] + rs2[1] + rs2[2] + rs2[3];
    float mean = S * (1.f / 2048.f);
    float var  = S2 * (1.f / 2048.f) - mean * mean;
    float g  = (c < 256) ? g0[c] : g1[c - 256];
    float be = (c < 256) ? be0[c] : be1[c - 256];
    float sc = g / sqrtf(var + 1e-5f);
    scale[c] = sc;
    shift[c] = be - mean * sc;
  }
}

// ------------------------------------------------------------------ ab ------
// grid 352: blocks 0..255 = ab GEMM; 256..351 = wsplit (independent work).
__global__ __launch_bounds__(256) void ab_kernel(
    const float* __restrict__ yG, const float* __restrict__ scale,
    const float* __restrict__ shift, const float* __restrict__ mask,
    const float* __restrict__ w0,
    const float* __restrict__ w1, const float* __restrict__ w2,
    const float* __restrict__ w3, uint32_t* __restrict__ wpk,
    float* __restrict__ a_arr, float* __restrict__ bb_arr)
{
  int bx = blockIdx.x;
  int tid = threadIdx.x;
  if (bx >= 256) {
    // ---- wsplit: wpk planes Wh / Wl (f16 pairs along k) ----
    int e = (bx - 256) * 256 + tid;       // 0..24575 (L, k2, n)
    int L = e >> 13;
    int r = e & 8191;
    int k2 = r >> 7, n = r & 127;
    int k = k2 * 2;
    const float* w = (L == 0) ? w1 : (L == 1) ? w2 : w3;
    uint32_t hw, lw;
    split2(w[k * 128 + n], w[(k + 1) * 128 + n], hw, lw);
    wpk[L * 8192 + n * 64 + k2] = hw;
    wpk[24576 + L * 8192 + n * 64 + k2] = lw;
    return;
  }
  __shared__ float As[32 * 36];
  __shared__ float Ws[32 * 68];
  int rt = bx & 63, ct = bx >> 6;
  int row0 = rt * 32, n0 = ct * 64;
  int r4 = (tid >> 5) * 4;
  int n2 = (tid & 31) * 2;
  int scc = tid >> 3, srr4 = (tid & 7) * 4;
  int wnn8 = (tid & 7) * 8;
  const float* wbase = (n0 < 128) ? (w0 + n0) : (w0 + CCH * 128 + (n0 - 128));
  float4 mv = *(const float4*)(mask + row0 + srr4);

  float acc[4][2] = {{0.f, 0.f}};
#pragma unroll 1
  for (int c0 = 0; c0 < 384; c0 += 32) {
    int c = c0 + scc;
    float4 yv;
    if (c < 256) {
      yv = *(const float4*)(yG + c * 2048 + row0 + srr4);
    } else {
      int cc = c - 256;
      yv = *(const float4*)(yG + (384 + cc) * 2048 + row0 + srr4);
      if (rt > 0) {
        float4 u = *(const float4*)(yG + (256 + cc) * 2048 + row0 + srr4 - 32);
        yv.x += u.x; yv.y += u.y; yv.z += u.z; yv.w += u.w;
      }
      if (rt < 63) {
        float4 u = *(const float4*)(yG + (512 + cc) * 2048 + row0 + srr4 + 32);
        yv.x += u.x; yv.y += u.y; yv.z += u.z; yv.w += u.w;
      }
    }
    float sc = scale[c], sh = shift[c];
    float4 wv0 = *(const float4*)(wbase + c * 128 + wnn8);
    float4 wv1 = *(const float4*)(wbase + c * 128 + wnn8 + 4);
    __syncthreads();
    float4 hv;
    hv.x = leaky(fmaf(yv.x, sc, sh)) * mv.x;
    hv.y = leaky(fmaf(yv.y, sc, sh)) * mv.y;
    hv.z = leaky(fmaf(yv.z, sc, sh)) * mv.z;
    hv.w = leaky(fmaf(yv.w, sc, sh)) * mv.w;
    *(float4*)&As[scc * 36 + srr4] = hv;
    *(float4*)&Ws[scc * 68 + wnn8] = wv0;
    *(float4*)&Ws[scc * 68 + wnn8 + 4] = wv1;
    __syncthreads();
#pragma unroll
    for (int cc = 0; cc < 32; ++cc) {
      float4 a = *(const float4*)&As[cc * 36 + r4];
      float2 w = *(const float2*)&Ws[cc * 68 + n2];
      acc[0][0] = fmaf(a.x, w.x, acc[0][0]); acc[0][1] = fmaf(a.x, w.y, acc[0][1]);
      acc[1][0] = fmaf(a.y, w.x, acc[1][0]); acc[1][1] = fmaf(a.y, w.y, acc[1][1]);
      acc[2][0] = fmaf(a.z, w.x, acc[2][0]); acc[2][1] = fmaf(a.z, w.y, acc[2][1]);
      acc[3][0] = fmaf(a.w, w.x, acc[3][0]); acc[3][1] = fmaf(a.w, w.y, acc[3][1]);
    }
  }
  float* dst; int nd;
  if (n0 < 128) { dst = a_arr; nd = n0; } else { dst = bb_arr; nd = n0 - 128; }
#pragma unroll
  for (int ri = 0; ri < 4; ++ri)
    *(float2*)&dst[(row0 + r4 + ri) * 128 + nd + n2] = make_float2(acc[ri][0], acc[ri][1]);
}

// ---------------------------------------------------------------- pair ------
// grid (64,16), 512 threads = 8 waves (2m x 4n). LDS 68KB -> 2 blocks/CU.
// Fused epilogue with parallel-friendly load shape (see header).
__global__ __launch_bounds__(512) void pair_kernel(
    const float* __restrict__ a_arr, const float* __restrict__ bb_arr,
    const float* __restrict__ b0, const uint32_t* __restrict__ wpk,
    const float* __restrict__ b1, const float* __restrict__ b2,
    const float* __restrict__ b3,
    const float* __restrict__ w4, const float* __restrict__ b4,
    const float* __restrict__ w5, const float* __restrict__ b5,
    const float* __restrict__ mask, float* __restrict__ out)
{
  __shared__ uint32_t Ahs[128 * 68];
  __shared__ uint32_t Als[128 * 68];
  int i = blockIdx.x, bp = blockIdx.y;
  int tid = threadIdx.x;

  // ---- init: p0 = leaky(a_i + bb_j + b0) -> split planes ----
#pragma unroll 1
  for (int it = 0; it < 4; ++it) {
    int idx = it * 512 + tid;            // 0..2047
    int r   = idx >> 4;                  // 0..127
    int k8  = (idx & 15) * 8;
    int db  = r >> 6, j = r & 63;
    int bq  = bp * 2 + db;
    const float* ap = a_arr + (i * BB + bq) * 128 + k8;
    const float* bbp = bb_arr + (j * BB + bq) * 128 + k8;
    const float* zp = b0 + k8;
    float d[8];
#pragma unroll
    for (int t = 0; t < 8; t += 4) {
      float4 av = *(const float4*)(ap + t);
      float4 bv = *(const float4*)(bbp + t);
      float4 zv = *(const float4*)(zp + t);
      d[t+0] = leaky(av.x + bv.x + zv.x);
      d[t+1] = leaky(av.y + bv.y + zv.y);
      d[t+2] = leaky(av.z + bv.z + zv.z);
      d[t+3] = leaky(av.w + bv.w + zv.w);
    }
    uint4 hq, lq;
    split2(d[0], d[1], hq.x, lq.x);
    split2(d[2], d[3], hq.y, lq.y);
    split2(d[4], d[5], hq.z, lq.z);
    split2(d[6], d[7], hq.w, lq.w);
    *(uint4*)&Ahs[r * 68 + k8 / 2] = hq;
    *(uint4*)&Als[r * 68 + k8 / 2] = lq;
  }
  __syncthreads();

  int wid = __builtin_amdgcn_readfirstlane(tid >> 6);
  int wm = wid & 1, wn = wid >> 1;       // m-half (=batch), n-quarter
  int lane = tid & 63;
  int m16 = lane & 15, q = lane >> 4;

  f32x4 hi[4][2], cr[4][2];

#pragma unroll 1
  for (int L = 0; L < 3; ++L) {
    const uint32_t* WhL = wpk + L * 8192;
    const uint32_t* WlL = wpk + 24576 + L * 8192;
    const float* Bv = (L == 0) ? b1 : (L == 1) ? b2 : b3;
#pragma unroll
    for (int mt = 0; mt < 4; ++mt)
#pragma unroll
      for (int nt = 0; nt < 2; ++nt) {
        hi[mt][nt] = (f32x4){0.f, 0.f, 0.f, 0.f};
        cr[mt][nt] = (f32x4){0.f, 0.f, 0.f, 0.f};
      }

    // prefetch ks=0 W frags
    F8 Wh[2], Wl[2], Whn[2], Wln[2];
#pragma unroll
    for (int nt = 0; nt < 2; ++nt) {
      int wrow = wn * 32 + nt * 16 + m16;
      Wh[nt].q = *(const uint4*)(WhL + wrow * 64 + q * 4);
      Wl[nt].q = *(const uint4*)(WlL + wrow * 64 + q * 4);
    }

#pragma unroll
    for (int ks = 0; ks < 4; ++ks) {
      int koff2 = ks * 16 + q * 4;
      if (ks < 3) {
#pragma unroll
        for (int nt = 0; nt < 2; ++nt) {
          int wrow = wn * 32 + nt * 16 + m16;
          Whn[nt].q = *(const uint4*)(WhL + wrow * 64 + koff2 + 16);
          Wln[nt].q = *(const uint4*)(WlL + wrow * 64 + koff2 + 16);
        }
      }
#pragma unroll
      for (int mt = 0; mt < 4; ++mt) {
        int arow = wm * 64 + mt * 16 + m16;
        F8 Ah, Al;
        Ah.q = *(const uint4*)&Ahs[arow * 68 + koff2];
        Al.q = *(const uint4*)&Als[arow * 68 + koff2];
#pragma unroll
        for (int nt = 0; nt < 2; ++nt) {
          hi[mt][nt] = __builtin_amdgcn_mfma_f32_16x16x32_f16(
              Ah.h, Wh[nt].h, hi[mt][nt], 0, 0, 0);
          cr[mt][nt] = __builtin_amdgcn_mfma_f32_16x16x32_f16(
              Ah.h, Wl[nt].h, cr[mt][nt], 0, 0, 0);
          cr[mt][nt] = __builtin_amdgcn_mfma_f32_16x16x32_f16(
              Al.h, Wh[nt].h, cr[mt][nt], 0, 0, 0);
        }
      }
#pragma unroll
      for (int nt = 0; nt < 2; ++nt) { Wh[nt] = Whn[nt]; Wl[nt] = Wln[nt]; }
    }

    float bias[2];
#pragma unroll
    for (int nt = 0; nt < 2; ++nt) bias[nt] = Bv[wn * 32 + nt * 16 + m16];

    if (L < 2) {
      __syncthreads();                   // all frag reads of this layer done
      int par = lane & 1;
#pragma unroll
      for (int mt = 0; mt < 4; ++mt)
#pragma unroll
        for (int nt = 0; nt < 2; ++nt) {
          int colw = (wn * 32 + nt * 16 + (m16 & ~1)) >> 1;
#pragma unroll
          for (int rg = 0; rg < 4; ++rg) {
            float d = leaky(hi[mt][nt][rg] + cr[mt][nt][rg] * (1.0f / 2048.0f)
                            + bias[nt]);
            float dn = __shfl_xor(d, 1, 64);
            float de = par ? dn : d;     // even-col value
            float do_ = par ? d : dn;    // odd-col value
            uint32_t hw, lw;
            split2(de, do_, hw, lw);
            int row = wm * 64 + mt * 16 + q * 4 + rg;
            if (par) Als[row * 68 + colw] = lw;
            else     Ahs[row * 68 + colw] = hw;
          }
        }
      __syncthreads();
    } else {
      // ---- j-mean + fused output MLP (parallel-friendly epilogue) ----
      float s[2] = {0.f, 0.f};
#pragma unroll
      for (int nt = 0; nt < 2; ++nt)
#pragma unroll
        for (int mt = 0; mt < 4; ++mt)
#pragma unroll
          for (int rg = 0; rg < 4; ++rg)
            s[nt] += leaky(hi[mt][nt][rg] + cr[mt][nt][rg] * (1.0f / 2048.0f)
                           + bias[nt]);
      int browp = i * BB + bp * 2 + wm;
      float mfac = (1.0f / 64.0f) * mask[browp];
#pragma unroll
      for (int nt = 0; nt < 2; ++nt) {
        s[nt] += __shfl_xor(s[nt], 16, 64);
        s[nt] += __shfl_xor(s[nt], 32, 64);
      }
      __syncthreads();                   // Ahs/Als reads done; reuse as scratch
      float* scratch = (float*)Ahs;
      float* Pm = scratch;               // [2][128]
      float* Tp = scratch + 256;         // [2][2][128] partials
      float* T4 = scratch + 768;         // [2][128]
      if (lane < 16) {
#pragma unroll
        for (int nt = 0; nt < 2; ++nt)
          Pm[wm * 128 + wn * 32 + nt * 16 + m16] = s[nt] * mfac;
      }
      __syncthreads();
      {
        // t4 partials: row = tid>>8, c-half = (tid>>7)&1, k = tid&127
        int row = tid >> 8;
        int ch  = (tid >> 7) & 1;
        int k   = tid & 127;
        const float* pm  = Pm + row * 128 + ch * 64;
        const float* w4c = w4 + ch * 64 * 128 + k;
        float t = ch ? 0.f : b4[k];
#pragma unroll 4
        for (int c0 = 0; c0 < 64; c0 += 4) {
          float4 pv = *(const float4*)&pm[c0];
          t = fmaf(pv.x, w4c[(c0 + 0) * 128], t);
          t = fmaf(pv.y, w4c[(c0 + 1) * 128], t);
          t = fmaf(pv.z, w4c[(c0 + 2) * 128], t);
          t = fmaf(pv.w, w4c[(c0 + 3) * 128], t);
        }
        Tp[(row * 2 + ch) * 128 + k] = t;
      }
      __syncthreads();
      if (tid < 256) {
        int row = tid >> 7, k = tid & 127;
        T4[row * 128 + k] = leaky(Tp[row * 256 + k] + Tp[row * 256 + 128 + k]);
      }
      __syncthreads();
      {
        // out: thread kk = tid computes BOTH rows from one w5 column stream
        int kk = tid;
        float o0 = b5[kk], o1 = o0;
#pragma unroll 4
        for (int c0 = 0; c0 < 128; c0 += 4) {
          float4 ta = *(const float4*)&T4[c0];
          float4 tb = *(const float4*)&T4[128 + c0];
          float w0v = w5[(c0 + 0) * 512 + kk];
          float w1v = w5[(c0 + 1) * 512 + kk];
          float w2v = w5[(c0 + 2) * 512 + kk];
          float w3v = w5[(c0 + 3) * 512 + kk];
          o0 = fmaf(ta.x, w0v, o0); o1 = fmaf(tb.x, w0v, o1);
          o0 = fmaf(ta.y, w1v, o0); o1 = fmaf(tb.y, w1v, o1);
          o0 = fmaf(ta.z, w2v, o0); o1 = fmaf(tb.z, w2v, o1);
          o0 = fmaf(ta.w, w3v, o0); o1 = fmaf(tb.w, w3v, o1);
        }
        int brow0 = i * BB + bp * 2;
        float m0 = mask[brow0], m1 = mask[brow0 + 1];
        out[brow0 * 512 + kk]       = leaky(o0) * m0;
        out[(brow0 + 1) * 512 + kk] = leaky(o1) * m1;
      }
    }
  }
}

// -------------------------------------------------------------- launch ------
extern "C" void kernel_launch(void* const* d_in, const int* in_sizes, int n_in,
                              void* d_out, int out_size, void* d_ws, size_t ws_size,
                              hipStream_t stream) {
  const float* x    = (const float*)d_in[0];
  const float* mask = (const float*)d_in[1];
  const float* cw0  = (const float*)d_in[2];
  // d_in[3] conv_b0: cancels in BN
  const float* g0   = (const float*)d_in[4];
  const float* be0  = (const float*)d_in[5];
  const float* cw1  = (const float*)d_in[6];
  // d_in[7] conv_b1: cancels in BN
  const float* g1   = (const float*)d_in[8];
  const float* be1  = (const float*)d_in[9];
  const float* w0   = (const float*)d_in[10];
  const float* b0   = (const float*)d_in[11];
  const float* w1   = (const float*)d_in[12];
  const float* b1   = (const float*)d_in[13];
  const float* w2   = (const float*)d_in[14];
  const float* b2   = (const float*)d_in[15];
  const float* w3   = (const float*)d_in[16];
  const float* b3   = (const float*)d_in[17];
  const float* w4   = (const float*)d_in[18];
  const float* b4   = (const float*)d_in[19];
  const float* w5   = (const float*)d_in[20];
  const float* b5   = (const float*)d_in[21];

  float* ws     = (float*)d_ws;
  float* yG     = ws;                    // 640*2048 = 1,310,720 words
  uint32_t* wpk = (uint32_t*)(ws + 1310720);  // 49152 words (live through pair)
  float* scale  = ws + 1359872;          // 384
  float* shift  = ws + 1360256;          // 384
  float* a_arr  = ws + 1360640;          // 2048*128
  float* bb_arr = ws + 1622784;          // 2048*128
  float* outp   = (float*)d_out;

  conv_kernel<<<320, 256, 0, stream>>>(x, mask, cw0, cw1, yG);
  stats_kernel<<<384, 256, 0, stream>>>(yG, g0, be0, g1, be1, scale, shift);
  ab_kernel<<<352, 256, 0, stream>>>(yG, scale, shift, mask, w0,
                                     w1, w2, w3, wpk, a_arr, bb_arr);
  dim3 g5(64, 16);
  pair_kernel<<<g5, 512, 0, stream>>>(a_arr, bb_arr, b0, wpk, b1, b2, b3,
                                      w4, b4, w5, b5, mask, outp);
}

// Round 12
// 257.760 us; speedup vs baseline: 1.2544x; 1.0080x over previous
//
#include <hip/hip_runtime.h>

// RelationLayer, round 12.
// R11 (cooperative mega-kernel) failed at launch (poison output = never ran;
// cooperative occupancy validation likely rejects 68KB-LDS blocks). Revised
// accounting: conv is genuinely LDS-bound (~3:1 LDS:VALU, ~35-45us) -- fix the
// kernel, not the launch count.
// R12: conv rewritten as fp16-split MFMA GEMM (pair's proven machinery):
//  * 192 blocks (32 m-tiles x 6 n-tiles of 64x64), 256 thr = 4 waves (2m x 2n).
//  * K chunked by 128: x*mask and conv-w split into hi/lo f16 LDS planes
//    (stride 68 words), frags fed to mfma_f32_16x16x32_f16 (3 products).
//  * win3 = ONE K=1536 GEMM: taps in-K via +-32-row-shifted zero-padded A
//    reads -> yG comes out RECOMBINED (384 channels).
//  * BN stats fused: block owns complete y tile -> per-channel sum/sumsq
//    shuffle-reduced, one atomicAdd pair per channel per block.
// stats_kernel deleted; ab computes scale/shift inline from the atomic sums
// and loses the 3-tap recombine. pair = R10 verbatim (115.7us measured).

#define BB 32
#define CCH 384

__device__ __forceinline__ float leaky(float x) { return fmaxf(x, 0.1f * x); }

typedef _Float16 f16x8 __attribute__((ext_vector_type(8)));
typedef float f32x4 __attribute__((ext_vector_type(4)));

union F8 { uint4 q; f16x8 h; };
union H2 { _Float16 f[2]; uint32_t u; };

__device__ __forceinline__ void split2(float d0, float d1,
                                       uint32_t& hw, uint32_t& lw) {
  H2 h, l;
  h.f[0] = (_Float16)d0; h.f[1] = (_Float16)d1;
  l.f[0] = (_Float16)((d0 - (float)h.f[0]) * 2048.0f);
  l.f[1] = (_Float16)((d1 - (float)h.f[1]) * 2048.0f);
  hw = h.u; lw = l.u;
}

// ---------------------------------------------------------------- conv ------
// grid 192 = 32 m-tiles(64 rows) x 6 n-tiles(64 ch): nb 0..3 win1 (K=512),
// nb 4..5 win3 (K=1536, taps in-K). Output yG[c][row] recombined, c<384.
__global__ __launch_bounds__(256) void conv_kernel(
    const float* __restrict__ x, const float* __restrict__ mask,
    const float* __restrict__ cw0, const float* __restrict__ cw1,
    float* __restrict__ yG, float* __restrict__ Ssum, float* __restrict__ Ssq)
{
  __shared__ uint32_t Ah[64 * 68], Al[64 * 68];
  __shared__ uint32_t Bh[64 * 68], Bl[64 * 68];
  int bx = blockIdx.x;
  int nb = bx % 6, mb = bx / 6;
  int n0 = nb * 64;
  int row0 = mb * 64;
  bool w3 = (nb >= 4);
  int nch = w3 ? 12 : 4;
  const float* wbase = w3 ? (cw1 + (n0 - 256) * 1536) : (cw0 + n0 * 512);
  int wK = w3 ? 1536 : 512;

  int tid = threadIdx.x;
  int wid = __builtin_amdgcn_readfirstlane(tid >> 6);
  int wm = wid & 1, wn2 = wid >> 1;
  int lane = tid & 63;
  int m16 = lane & 15, q = lane >> 4;

  f32x4 hi[2][2], cr[2][2];
#pragma unroll
  for (int a = 0; a < 2; ++a)
#pragma unroll
    for (int b = 0; b < 2; ++b) {
      hi[a][b] = (f32x4){0.f, 0.f, 0.f, 0.f};
      cr[a][b] = (f32x4){0.f, 0.f, 0.f, 0.f};
    }

#pragma unroll 1
  for (int ch = 0; ch < nch; ++ch) {
    int kg0 = ch * 128;
    int tap = kg0 >> 9;
    int d0 = kg0 & 511;
    int shift = w3 ? (tap - 1) * 32 : 0;
    __syncthreads();                     // prior chunk's frag reads done
#pragma unroll 1
    for (int it = 0; it < 4; ++it) {
      int idx = it * 256 + tid;
      int r = idx >> 4;                  // 0..63
      int k8 = (idx & 15) * 8;           // 0..120
      // A: x * mask, row-shifted per tap, zero-padded at edges
      float d[8];
      int rowg = row0 + r + shift;
      if ((unsigned)rowg < 2048u) {
        float mv = mask[rowg];
        const float* xp = x + rowg * 512 + d0 + k8;
        float4 a0 = *(const float4*)xp;
        float4 a1 = *(const float4*)(xp + 4);
        d[0] = a0.x * mv; d[1] = a0.y * mv; d[2] = a0.z * mv; d[3] = a0.w * mv;
        d[4] = a1.x * mv; d[5] = a1.y * mv; d[6] = a1.z * mv; d[7] = a1.w * mv;
      } else {
#pragma unroll
        for (int t2 = 0; t2 < 8; ++t2) d[t2] = 0.f;
      }
      uint4 hq, lq;
      split2(d[0], d[1], hq.x, lq.x);
      split2(d[2], d[3], hq.y, lq.y);
      split2(d[4], d[5], hq.z, lq.z);
      split2(d[6], d[7], hq.w, lq.w);
      *(uint4*)&Ah[r * 68 + k8 / 2] = hq;
      *(uint4*)&Al[r * 68 + k8 / 2] = lq;
      // B: conv weights (cw1 k-layout is already tap-major -> direct)
      const float* wp = wbase + r * wK + kg0 + k8;
      float4 b0v = *(const float4*)wp;
      float4 b1v = *(const float4*)(wp + 4);
      split2(b0v.x, b0v.y, hq.x, lq.x);
      split2(b0v.z, b0v.w, hq.y, lq.y);
      split2(b1v.x, b1v.y, hq.z, lq.z);
      split2(b1v.z, b1v.w, hq.w, lq.w);
      *(uint4*)&Bh[r * 68 + k8 / 2] = hq;
      *(uint4*)&Bl[r * 68 + k8 / 2] = lq;
    }
    __syncthreads();
#pragma unroll
    for (int ks = 0; ks < 4; ++ks) {
      int koff = ks * 16 + q * 4;
      F8 bh[2], bl[2];
#pragma unroll
      for (int nt = 0; nt < 2; ++nt) {
        int br = wn2 * 32 + nt * 16 + m16;
        bh[nt].q = *(const uint4*)&Bh[br * 68 + koff];
        bl[nt].q = *(const uint4*)&Bl[br * 68 + koff];
      }
#pragma unroll
      for (int mt = 0; mt < 2; ++mt) {
        int ar = wm * 32 + mt * 16 + m16;
        F8 ah, al;
        ah.q = *(const uint4*)&Ah[ar * 68 + koff];
        al.q = *(const uint4*)&Al[ar * 68 + koff];
#pragma unroll
        for (int nt = 0; nt < 2; ++nt) {
          hi[mt][nt] = __builtin_amdgcn_mfma_f32_16x16x32_f16(
              ah.h, bh[nt].h, hi[mt][nt], 0, 0, 0);
          cr[mt][nt] = __builtin_amdgcn_mfma_f32_16x16x32_f16(
              ah.h, bl[nt].h, cr[mt][nt], 0, 0, 0);
          cr[mt][nt] = __builtin_amdgcn_mfma_f32_16x16x32_f16(
              al.h, bh[nt].h, cr[mt][nt], 0, 0, 0);
        }
      }
    }
  }

  // combine products
  float y[2][2][4];
#pragma unroll
  for (int mt = 0; mt < 2; ++mt)
#pragma unroll
    for (int nt = 0; nt < 2; ++nt)
#pragma unroll
      for (int rg = 0; rg < 4; ++rg)
        y[mt][nt][rg] = hi[mt][nt][rg] + cr[mt][nt][rg] * (1.0f / 2048.0f);

  // fused BN stats: per-channel sum / sumsq over this block's 64 rows
#pragma unroll
  for (int nt = 0; nt < 2; ++nt) {
    float s = 0.f, s2 = 0.f;
#pragma unroll
    for (int mt = 0; mt < 2; ++mt)
#pragma unroll
      for (int rg = 0; rg < 4; ++rg) {
        float v = y[mt][nt][rg];
        s += v; s2 += v * v;
      }
    s  += __shfl_xor(s, 16, 64);  s  += __shfl_xor(s, 32, 64);
    s2 += __shfl_xor(s2, 16, 64); s2 += __shfl_xor(s2, 32, 64);
    if (lane < 16) {
      int c = n0 + wn2 * 32 + nt * 16 + m16;
      atomicAdd(&Ssum[c], s);
      atomicAdd(&Ssq[c], s2);
    }
  }

  // store yG[c][row] via LDS transpose (coalesced 64B runs)
  __syncthreads();
  float* Yl = (float*)Ah;                // 64 x 68 floats (fits in Ah)
#pragma unroll
  for (int mt = 0; mt < 2; ++mt)
#pragma unroll
    for (int nt = 0; nt < 2; ++nt)
#pragma unroll
      for (int rg = 0; rg < 4; ++rg)
        Yl[(wn2 * 32 + nt * 16 + m16) * 68 + wm * 32 + mt * 16 + q * 4 + rg] =
            y[mt][nt][rg];
  __syncthreads();
  {
    int c = tid >> 2, seg = (tid & 3) * 16;
#pragma unroll
    for (int j = 0; j < 16; j += 4)
      *(float4*)&yG[(n0 + c) * 2048 + row0 + seg + j] =
          *(const float4*)&Yl[c * 68 + seg + j];
  }
}

// ------------------------------------------------------------------ ab ------
// grid 352: blocks 0..255 = ab GEMM (scale/shift computed inline from atomic
// sums); 256..351 = wsplit for w1..w3.
__global__ __launch_bounds__(256) void ab_kernel(
    const float* __restrict__ yG, const float* __restrict__ Ssum,
    const float* __restrict__ Ssq,
    const float* __restrict__ g0, const float* __restrict__ be0,
    const float* __restrict__ g1, const float* __restrict__ be1,
    const float* __restrict__ mask, const float* __restrict__ w0,
    const float* __restrict__ w1, const float* __restrict__ w2,
    const float* __restrict__ w3, uint32_t* __restrict__ wpk,
    float* __restrict__ a_arr, float* __restrict__ bb_arr)
{
  int bx = blockIdx.x;
  int tid = threadIdx.x;
  if (bx >= 256) {
    int e = (bx - 256) * 256 + tid;       // 0..24575 (L, k2, n)
    int L = e >> 13;
    int r = e & 8191;
    int k2 = r >> 7, n = r & 127;
    int k = k2 * 2;
    const float* w = (L == 0) ? w1 : (L == 1) ? w2 : w3;
    uint32_t hw, lw;
    split2(w[k * 128 + n], w[(k + 1) * 128 + n], hw, lw);
    wpk[L * 8192 + n * 64 + k2] = hw;
    wpk[24576 + L * 8192 + n * 64 + k2] = lw;
    return;
  }
  __shared__ float As[32 * 36];
  __shared__ float Ws[32 * 68];
  __shared__ float scs[384], shs[384];
  // scale/shift from fused-atomics stats (BN + gamma/beta fold)
  for (int c = tid; c < 384; c += 256) {
    float Sv = Ssum[c], S2v = Ssq[c];
    float mean = Sv * (1.f / 2048.f);
    float var  = S2v * (1.f / 2048.f) - mean * mean;
    float g  = (c < 256) ? g0[c] : g1[c - 256];
    float be = (c < 256) ? be0[c] : be1[c - 256];
    float sc = g / sqrtf(var + 1e-5f);
    scs[c] = sc;
    shs[c] = be - mean * sc;
  }
  __syncthreads();

  int rt = bx & 63, ct = bx >> 6;
  int row0 = rt * 32, n0 = ct * 64;
  int r4 = (tid >> 5) * 4;
  int n2 = (tid & 31) * 2;
  int scc = tid >> 3, srr4 = (tid & 7) * 4;
  int wnn8 = (tid & 7) * 8;
  const float* wbase = (n0 < 128) ? (w0 + n0) : (w0 + CCH * 128 + (n0 - 128));
  float4 mv = *(const float4*)(mask + row0 + srr4);

  float acc[4][2] = {{0.f, 0.f}};
#pragma unroll 1
  for (int c0 = 0; c0 < 384; c0 += 32) {
    int c = c0 + scc;
    float4 yv = *(const float4*)(yG + c * 2048 + row0 + srr4);
    float sc = scs[c], sh = shs[c];
    float4 wv0 = *(const float4*)(wbase + c * 128 + wnn8);
    float4 wv1 = *(const float4*)(wbase + c * 128 + wnn8 + 4);
    __syncthreads();
    float4 hv;
    hv.x = leaky(fmaf(yv.x, sc, sh)) * mv.x;
    hv.y = leaky(fmaf(yv.y, sc, sh)) * mv.y;
    hv.z = leaky(fmaf(yv.z, sc, sh)) * mv.z;
    hv.w = leaky(fmaf(yv.w, sc, sh)) * mv.w;
    *(float4*)&As[scc * 36 + srr4] = hv;
    *(float4*)&Ws[scc * 68 + wnn8] = wv0;
    *(float4*)&Ws[scc * 68 + wnn8 + 4] = wv1;
    __syncthreads();
#pragma unroll
    for (int cc = 0; cc < 32; ++cc) {
      float4 a = *(const float4*)&As[cc * 36 + r4];
      float2 w = *(const float2*)&Ws[cc * 68 + n2];
      acc[0][0] = fmaf(a.x, w.x, acc[0][0]); acc[0][1] = fmaf(a.x, w.y, acc[0][1]);
      acc[1][0] = fmaf(a.y, w.x, acc[1][0]); acc[1][1] = fmaf(a.y, w.y, acc[1][1]);
      acc[2][0] = fmaf(a.z, w.x, acc[2][0]); acc[2][1] = fmaf(a.z, w.y, acc[2][1]);
      acc[3][0] = fmaf(a.w, w.x, acc[3][0]); acc[3][1] = fmaf(a.w, w.y, acc[3][1]);
    }
  }
  float* dst; int nd;
  if (n0 < 128) { dst = a_arr; nd = n0; } else { dst = bb_arr; nd = n0 - 128; }
#pragma unroll
  for (int ri = 0; ri < 4; ++ri)
    *(float2*)&dst[(row0 + r4 + ri) * 128 + nd + n2] = make_float2(acc[ri][0], acc[ri][1]);
}

// ---------------------------------------------------------------- pair ------
// R10 verbatim: grid (64,16), 512 thr = 8 waves (2m x 4n), LDS 68KB,
// fused parallel-friendly epilogue.
__global__ __launch_bounds__(512) void pair_kernel(
    const float* __restrict__ a_arr, const float* __restrict__ bb_arr,
    const float* __restrict__ b0, const uint32_t* __restrict__ wpk,
    const float* __restrict__ b1, const float* __restrict__ b2,
    const float* __restrict__ b3,
    const float* __restrict__ w4, const float* __restrict__ b4,
    const float* __restrict__ w5, const float* __restrict__ b5,
    const float* __restrict__ mask, float* __restrict__ out)
{
  __shared__ uint32_t Ahs[128 * 68];
  __shared__ uint32_t Als[128 * 68];
  int i = blockIdx.x, bp = blockIdx.y;
  int tid = threadIdx.x;

#pragma unroll 1
  for (int it = 0; it < 4; ++it) {
    int idx = it * 512 + tid;
    int r   = idx >> 4;
    int k8  = (idx & 15) * 8;
    int db  = r >> 6, j = r & 63;
    int bq  = bp * 2 + db;
    const float* ap = a_arr + (i * BB + bq) * 128 + k8;
    const float* bbp = bb_arr + (j * BB + bq) * 128 + k8;
    const float* zp = b0 + k8;
    float d[8];
#pragma unroll
    for (int t = 0; t < 8; t += 4) {
      float4 av = *(const float4*)(ap + t);
      float4 bv = *(const float4*)(bbp + t);
      float4 zv = *(const float4*)(zp + t);
      d[t+0] = leaky(av.x + bv.x + zv.x);
      d[t+1] = leaky(av.y + bv.y + zv.y);
      d[t+2] = leaky(av.z + bv.z + zv.z);
      d[t+3] = leaky(av.w + bv.w + zv.w);
    }
    uint4 hq, lq;
    split2(d[0], d[1], hq.x, lq.x);
    split2(d[2], d[3], hq.y, lq.y);
    split2(d[4], d[5], hq.z, lq.z);
    split2(d[6], d[7], hq.w, lq.w);
    *(uint4*)&Ahs[r * 68 + k8 / 2] = hq;
    *(uint4*)&Als[r * 68 + k8 / 2] = lq;
  }
  __syncthreads();

  int wid = __builtin_amdgcn_readfirstlane(tid >> 6);
  int wm = wid & 1, wn = wid >> 1;
  int lane = tid & 63;
  int m16 = lane & 15, q = lane >> 4;

  f32x4 hi[4][2], cr[4][2];

#pragma unroll 1
  for (int L = 0; L < 3; ++L) {
    const uint32_t* WhL = wpk + L * 8192;
    const uint32_t* WlL = wpk + 24576 + L * 8192;
    const float* Bv = (L == 0) ? b1 : (L == 1) ? b2 : b3;
#pragma unroll
    for (int mt = 0; mt < 4; ++mt)
#pragma unroll
      for (int nt = 0; nt < 2; ++nt) {
        hi[mt][nt] = (f32x4){0.f, 0.f, 0.f, 0.f};
        cr[mt][nt] = (f32x4){0.f, 0.f, 0.f, 0.f};
      }

    F8 Wh[2], Wl[2], Whn[2], Wln[2];
#pragma unroll
    for (int nt = 0; nt < 2; ++nt) {
      int wrow = wn * 32 + nt * 16 + m16;
      Wh[nt].q = *(const uint4*)(WhL + wrow * 64 + q * 4);
      Wl[nt].q = *(const uint4*)(WlL + wrow * 64 + q * 4);
    }

#pragma unroll
    for (int ks = 0; ks < 4; ++ks) {
      int koff2 = ks * 16 + q * 4;
      if (ks < 3) {
#pragma unroll
        for (int nt = 0; nt < 2; ++nt) {
          int wrow = wn * 32 + nt * 16 + m16;
          Whn[nt].q = *(const uint4*)(WhL + wrow * 64 + koff2 + 16);
          Wln[nt].q = *(const uint4*)(WlL + wrow * 64 + koff2 + 16);
        }
      }
#pragma unroll
      for (int mt = 0; mt < 4; ++mt) {
        int arow = wm * 64 + mt * 16 + m16;
        F8 Ah, Al;
        Ah.q = *(const uint4*)&Ahs[arow * 68 + koff2];
        Al.q = *(const uint4*)&Als[arow * 68 + koff2];
#pragma unroll
        for (int nt = 0; nt < 2; ++nt) {
          hi[mt][nt] = __builtin_amdgcn_mfma_f32_16x16x32_f16(
              Ah.h, Wh[nt].h, hi[mt][nt], 0, 0, 0);
          cr[mt][nt] = __builtin_amdgcn_mfma_f32_16x16x32_f16(
              Ah.h, Wl[nt].h, cr[mt][nt], 0, 0, 0);
          cr[mt][nt] = __builtin_amdgcn_mfma_f32_16x16x32_f16(
              Al.h, Wh[nt].h, cr[mt][nt], 0, 0, 0);
        }
      }
#pragma unroll
      for (int nt = 0; nt < 2; ++nt) { Wh[nt] = Whn[nt]; Wl[nt] = Wln[nt]; }
    }

    float bias[2];
#pragma unroll
    for (int nt = 0; nt < 2; ++nt) bias[nt] = Bv[wn * 32 + nt * 16 + m16];

    if (L < 2) {
      __syncthreads();
      int par = lane & 1;
#pragma unroll
      for (int mt = 0; mt < 4; ++mt)
#pragma unroll
        for (int nt = 0; nt < 2; ++nt) {
          int colw = (wn * 32 + nt * 16 + (m16 & ~1)) >> 1;
#pragma unroll
          for (int rg = 0; rg < 4; ++rg) {
            float d = leaky(hi[mt][nt][rg] + cr[mt][nt][rg] * (1.0f / 2048.0f)
                            + bias[nt]);
            float dn = __shfl_xor(d, 1, 64);
            float de = par ? dn : d;
            float do_ = par ? d : dn;
            uint32_t hw, lw;
            split2(de, do_, hw, lw);
            int row = wm * 64 + mt * 16 + q * 4 + rg;
            if (par) Als[row * 68 + colw] = lw;
            else     Ahs[row * 68 + colw] = hw;
          }
        }
      __syncthreads();
    } else {
      float s[2] = {0.f, 0.f};
#pragma unroll
      for (int nt = 0; nt < 2; ++nt)
#pragma unroll
        for (int mt = 0; mt < 4; ++mt)
#pragma unroll
          for (int rg = 0; rg < 4; ++rg)
            s[nt] += leaky(hi[mt][nt][rg] + cr[mt][nt][rg] * (1.0f / 2048.0f)
                           + bias[nt]);
      int browp = i * BB + bp * 2 + wm;
      float mfac = (1.0f / 64.0f) * mask[browp];
#pragma unroll
      for (int nt = 0; nt < 2; ++nt) {
        s[nt] += __shfl_xor(s[nt], 16, 64);
        s[nt] += __shfl_xor(s[nt], 32, 64);
      }
      __syncthreads();
      float* scratch = (float*)Ahs;
      float* Pm = scratch;
      float* Tp = scratch + 256;
      float* T4 = scratch + 768;
      if (lane < 16) {
#pragma unroll
        for (int nt = 0; nt < 2; ++nt)
          Pm[wm * 128 + wn * 32 + nt * 16 + m16] = s[nt] * mfac;
      }
      __syncthreads();
      {
        int row = tid >> 8;
        int chh = (tid >> 7) & 1;
        int k   = tid & 127;
        const float* pm  = Pm + row * 128 + chh * 64;
        const float* w4c = w4 + chh * 64 * 128 + k;
        float t = chh ? 0.f : b4[k];
#pragma unroll 4
        for (int c0 = 0; c0 < 64; c0 += 4) {
          float4 pv = *(const float4*)&pm[c0];
          t = fmaf(pv.x, w4c[(c0 + 0) * 128], t);
          t = fmaf(pv.y, w4c[(c0 + 1) * 128], t);
          t = fmaf(pv.z, w4c[(c0 + 2) * 128], t);
          t = fmaf(pv.w, w4c[(c0 + 3) * 128], t);
        }
        Tp[(row * 2 + chh) * 128 + k] = t;
      }
      __syncthreads();
      if (tid < 256) {
        int row = tid >> 7, k = tid & 127;
        T4[row * 128 + k] = leaky(Tp[row * 256 + k] + Tp[row * 256 + 128 + k]);
      }
      __syncthreads();
      {
        int kk = tid;
        float o0 = b5[kk], o1 = o0;
#pragma unroll 4
        for (int c0 = 0; c0 < 128; c0 += 4) {
          float4 ta = *(const float4*)&T4[c0];
          float4 tb = *(const float4*)&T4[128 + c0];
          float w0v = w5[(c0 + 0) * 512 + kk];
          float w1v = w5[(c0 + 1) * 512 + kk];
          float w2v = w5[(c0 + 2) * 512 + kk];
          float w3v = w5[(c0 + 3) * 512 + kk];
          o0 = fmaf(ta.x, w0v, o0); o1 = fmaf(tb.x, w0v, o1);
          o0 = fmaf(ta.y, w1v, o0); o1 = fmaf(tb.y, w1v, o1);
          o0 = fmaf(ta.z, w2v, o0); o1 = fmaf(tb.z, w2v, o1);
          o0 = fmaf(ta.w, w3v, o0); o1 = fmaf(tb.w, w3v, o1);
        }
        int brow0 = i * BB + bp * 2;
        float m0 = mask[brow0], m1 = mask[brow0 + 1];
        out[brow0 * 512 + kk]       = leaky(o0) * m0;
        out[(brow0 + 1) * 512 + kk] = leaky(o1) * m1;
      }
    }
  }
}

// -------------------------------------------------------------- launch ------
extern "C" void kernel_launch(void* const* d_in, const int* in_sizes, int n_in,
                              void* d_out, int out_size, void* d_ws, size_t ws_size,
                              hipStream_t stream) {
  const float* x    = (const float*)d_in[0];
  const float* mask = (const float*)d_in[1];
  const float* cw0  = (const float*)d_in[2];
  // d_in[3] conv_b0: cancels in BN
  const float* g0   = (const float*)d_in[4];
  const float* be0  = (const float*)d_in[5];
  const float* cw1  = (const float*)d_in[6];
  // d_in[7] conv_b1: cancels in BN
  const float* g1   = (const float*)d_in[8];
  const float* be1  = (const float*)d_in[9];
  const float* w0   = (const float*)d_in[10];
  const float* b0   = (const float*)d_in[11];
  const float* w1   = (const float*)d_in[12];
  const float* b1   = (const float*)d_in[13];
  const float* w2   = (const float*)d_in[14];
  const float* b2   = (const float*)d_in[15];
  const float* w3   = (const float*)d_in[16];
  const float* b3   = (const float*)d_in[17];
  const float* w4   = (const float*)d_in[18];
  const float* b4   = (const float*)d_in[19];
  const float* w5   = (const float*)d_in[20];
  const float* b5   = (const float*)d_in[21];

  float* ws     = (float*)d_ws;
  float* Ssum   = ws;                         // 384
  float* Ssq    = ws + 384;                   // 384
  float* yG     = ws + 768;                   // 384*2048 = 786432
  uint32_t* wpk = (uint32_t*)(ws + 787200);   // 49152
  float* a_arr  = ws + 836352;                // 2048*128
  float* bb_arr = ws + 1098496;               // 2048*128
  float* outp   = (float*)d_out;

  hipMemsetAsync(Ssum, 0, 768 * sizeof(float), stream);
  conv_kernel<<<192, 256, 0, stream>>>(x, mask, cw0, cw1, yG, Ssum, Ssq);
  ab_kernel<<<352, 256, 0, stream>>>(yG, Ssum, Ssq, g0, be0, g1, be1,
                                     mask, w0, w1, w2, w3, wpk, a_arr, bb_arr);
  dim3 g5(64, 16);
  pair_kernel<<<g5, 512, 0, stream>>>(a_arr, bb_arr, b0, wpk, b1, b2, b3,
                                      w4, b4, w5, b5, mask, outp);
}